// Round 4
// baseline (558.989 us; speedup 1.0000x reference)
//
#include <hip/hip_runtime.h>
#include <math.h>

#define NN   100000
#define EE   1600000
#define FIN  256
#define NCLS 16
#define NEG  0.2f

#define NEDGE (EE + NN)   // with self-loops
#define NBLK  ((NN + 255) / 256)   // 391 scan blocks

// ---- workspace layout (4-byte element offsets) ----
#define OFF_DEG   0                    // [NN] int, zeroed
#define OFF_CNT   (NN)                 // [NN] int, zeroed
#define NZERO_I   (2*NN)
#define OFF_ROW   (2*NN)               // [NN+1] int
#define OFF_TMP   (3*NN + 4)           // [NN] int
#define OFF_BSUM  (4*NN + 8)           // [512] int
#define OFF_ADJ   (4*NN + 520)         // [NEDGE] int (src per slot, CSR by dst)
#define OFF_H1B   (OFF_ADJ + NEDGE)    // [NN*64] bf16 -> NN*32 float slots
#define OFF_AL1S  (OFF_H1B + NN*32)    // [NN*8]
#define OFF_AL1D  (OFF_AL1S + NN*8)    // [NN*8]
#define OFF_H1    (OFF_AL1D + NN*8)    // [NN*64] fp32 (input to gemm2)
#define OFF_H2B   (OFF_H1 + NN*64)     // [NN*16] bf16 -> NN*8 float slots
#define OFF_AL2S  (OFF_H2B + NN*8)     // [NN]
#define OFF_AL2D  (OFF_AL2S + NN)      // [NN]

__device__ __forceinline__ float lrelu(float x) { return x >= 0.f ? x : NEG * x; }
__device__ __forceinline__ unsigned short f2bf(float x) {
    unsigned u = __float_as_uint(x);
    return (unsigned short)((u + 0x7FFF + ((u >> 16) & 1)) >> 16);   // RNE
}
__device__ __forceinline__ float bf2f(unsigned short b) {
    return __uint_as_float(((unsigned)b) << 16);
}

// ---------- CSR build ----------
__global__ __launch_bounds__(256) void k_hist(
    const int* __restrict__ edst, int* __restrict__ deg)
{
    int ei = blockIdx.x * 256 + threadIdx.x;
    if (ei >= NEDGE) return;
    int d = (ei < EE) ? edst[ei] : ei - EE;
    atomicAdd(&deg[d], 1);
}

__global__ __launch_bounds__(256) void k_scan1(
    const int* __restrict__ deg, int* __restrict__ tmp, int* __restrict__ bsum)
{
    __shared__ int s[256];
    int t = threadIdx.x;
    int i = blockIdx.x * 256 + t;
    int v = (i < NN) ? deg[i] : 0;
    s[t] = v;
    __syncthreads();
    for (int off = 1; off < 256; off <<= 1) {
        int u = (t >= off) ? s[t - off] : 0;
        __syncthreads();
        s[t] += u;
        __syncthreads();
    }
    if (i < NN) tmp[i] = s[t] - v;
    if (t == 255) bsum[blockIdx.x] = s[255];
}

__global__ __launch_bounds__(512) void k_scan2(int* __restrict__ bsum)
{
    __shared__ int s[512];
    int t = threadIdx.x;
    int v = (t < NBLK) ? bsum[t] : 0;
    s[t] = v;
    __syncthreads();
    for (int off = 1; off < 512; off <<= 1) {
        int u = (t >= off) ? s[t - off] : 0;
        __syncthreads();
        s[t] += u;
        __syncthreads();
    }
    bsum[t] = s[t] - v;
}

__global__ __launch_bounds__(256) void k_scan3(
    const int* __restrict__ tmp, const int* __restrict__ bsum,
    int* __restrict__ row)
{
    int i = blockIdx.x * 256 + threadIdx.x;
    if (i < NN) row[i] = tmp[i] + bsum[blockIdx.x];
    if (i == 0) row[NN] = NEDGE;
}

__global__ __launch_bounds__(256) void k_fill(
    const int* __restrict__ esrc, const int* __restrict__ edst,
    const int* __restrict__ row, int* __restrict__ cnt, int* __restrict__ adj)
{
    int ei = blockIdx.x * 256 + threadIdx.x;
    if (ei >= NEDGE) return;
    int s, d;
    if (ei < EE) { s = esrc[ei]; d = edst[ei]; } else { s = d = ei - EE; }
    int pos = row[d] + atomicAdd(&cnt[d], 1);
    adj[pos] = s;
}

// ---------- layer 1 GEMM: 64x64 tile, 4x4 register tile; bf16 value output ----------
__global__ __launch_bounds__(256) void k_gemm1(
    const float* __restrict__ x, const float* __restrict__ W1,
    const float* __restrict__ a1s, const float* __restrict__ a1d,
    unsigned short* __restrict__ h1b, float* __restrict__ al1s, float* __restrict__ al1d)
{
    __shared__ float sxT[32][68];
    __shared__ float sW[32][64];
    const int t = threadIdx.x;
    const int n0 = blockIdx.x * 64;
    const int tr = t >> 4, tc = t & 15;

    float acc[4][4] = {};

    for (int kc = 0; kc < 256; kc += 32) {
        __syncthreads();
        #pragma unroll
        for (int it = 0; it < 2; ++it) {
            int i = t + it * 256;
            int r = i >> 3, fj = i & 7;
            int n = n0 + r;
            float4 v = (n < NN) ? *(const float4*)(x + (size_t)n * FIN + kc + fj * 4)
                                : make_float4(0.f, 0.f, 0.f, 0.f);
            sxT[fj * 4 + 0][r] = v.x;
            sxT[fj * 4 + 1][r] = v.y;
            sxT[fj * 4 + 2][r] = v.z;
            sxT[fj * 4 + 3][r] = v.w;
        }
        #pragma unroll
        for (int it = 0; it < 2; ++it) {
            int i = t + it * 256;
            int r = i >> 4, fj = i & 15;
            *(float4*)&sW[r][fj * 4] = *(const float4*)(W1 + (size_t)(kc + r) * 64 + fj * 4);
        }
        __syncthreads();
        #pragma unroll
        for (int k = 0; k < 32; ++k) {
            float4 a = *(const float4*)&sxT[k][tr * 4];
            float4 b = *(const float4*)&sW[k][tc * 4];
            acc[0][0] += a.x * b.x; acc[0][1] += a.x * b.y; acc[0][2] += a.x * b.z; acc[0][3] += a.x * b.w;
            acc[1][0] += a.y * b.x; acc[1][1] += a.y * b.y; acc[1][2] += a.y * b.z; acc[1][3] += a.y * b.w;
            acc[2][0] += a.z * b.x; acc[2][1] += a.z * b.y; acc[2][2] += a.z * b.z; acc[2][3] += a.z * b.w;
            acc[3][0] += a.w * b.x; acc[3][1] += a.w * b.y; acc[3][2] += a.w * b.z; acc[3][3] += a.w * b.w;
        }
    }

    #pragma unroll
    for (int j = 0; j < 4; ++j) {
        int n = n0 + tr * 4 + j;
        if (n < NN) {
            ushort4 v = make_ushort4(f2bf(acc[j][0]), f2bf(acc[j][1]), f2bf(acc[j][2]), f2bf(acc[j][3]));
            *(ushort4*)(h1b + (size_t)n * 64 + tc * 4) = v;
        }
    }

    float sa[4], da[4];
    #pragma unroll
    for (int u = 0; u < 4; ++u) { sa[u] = a1s[tc * 4 + u]; da[u] = a1d[tc * 4 + u]; }
    #pragma unroll
    for (int j = 0; j < 4; ++j) {
        float vs = acc[j][0] * sa[0] + acc[j][1] * sa[1] + acc[j][2] * sa[2] + acc[j][3] * sa[3];
        float vd = acc[j][0] * da[0] + acc[j][1] * da[1] + acc[j][2] * da[2] + acc[j][3] * da[3];
        vs += __shfl_xor(vs, 1, 64);
        vd += __shfl_xor(vd, 1, 64);
        int n = n0 + tr * 4 + j;
        if (!(tc & 1) && n < NN) {
            al1s[n * 8 + (tc >> 1)] = vs;
            al1d[n * 8 + (tc >> 1)] = vd;
        }
    }
}

// ---------- layer 1 aggregation: fused max pre-pass + gather softmax + ELU ----------
__global__ __launch_bounds__(256) void k_agg1(
    const int* __restrict__ row, const int* __restrict__ adj,
    const float* __restrict__ al1s, const float* __restrict__ al1d,
    const unsigned short* __restrict__ h1b, const float* __restrict__ b1,
    float* __restrict__ h1)
{
    const int wv = threadIdx.x >> 6, lane = threadIdx.x & 63;
    const int n = blockIdx.x * 4 + wv;
    const int r0 = row[n], r1 = row[n + 1];

    // --- max pre-pass: 8 edges x 8 heads per iteration ---
    const int hh = lane & 7, jj = lane >> 3;
    const float ald_p = al1d[n * 8 + hh];
    float m = -1e30f;
    for (int i = r0 + jj; i < r1; i += 8) {
        int s = adj[i];
        m = fmaxf(m, lrelu(al1s[s * 8 + hh] + ald_p));
    }
    m = fmaxf(m, __shfl_xor(m, 8, 64));
    m = fmaxf(m, __shfl_xor(m, 16, 64));
    m = fmaxf(m, __shfl_xor(m, 32, 64));

    // --- main layout: lane = channel, head = lane>>3 ---
    const int h = lane >> 3;
    const float mh  = __shfl(m, h, 64);
    const float ald = __shfl(ald_p, h, 64);

    float dsum = 0.f, acc = 0.f;
    int i = r0;
    for (; i + 1 < r1; i += 2) {
        int s0 = adj[i], s1 = adj[i + 1];
        float e0 = lrelu(al1s[s0 * 8 + h] + ald);
        float e1 = lrelu(al1s[s1 * 8 + h] + ald);
        unsigned short u0 = h1b[(size_t)s0 * 64 + lane];
        unsigned short u1 = h1b[(size_t)s1 * 64 + lane];
        float w0 = __expf(e0 - mh), w1 = __expf(e1 - mh);
        dsum += w0 + w1;
        acc  += w0 * bf2f(u0) + w1 * bf2f(u1);
    }
    if (i < r1) {
        int s0 = adj[i];
        float e0 = lrelu(al1s[s0 * 8 + h] + ald);
        float w0 = __expf(e0 - mh);
        dsum += w0;
        acc  += w0 * bf2f(h1b[(size_t)s0 * 64 + lane]);
    }
    float v = acc / dsum + b1[lane];
    v = v > 0.f ? v : __expf(v) - 1.f;       // ELU fused
    h1[(size_t)n * 64 + lane] = v;
}

// ---------- layer 2 GEMM: h2b = bf16(h1 @ W2), al2s/al2d logits ----------
__global__ __launch_bounds__(256) void k_gemm2(
    const float* __restrict__ h1, const float* __restrict__ W2,
    const float* __restrict__ a2s, const float* __restrict__ a2d,
    unsigned short* __restrict__ h2b, float* __restrict__ al2s, float* __restrict__ al2d)
{
    __shared__ float sW[64 * 16];
    const int t = threadIdx.x;
    for (int i = t; i < 64 * 16; i += 256) sW[i] = W2[i];
    __syncthreads();
    const int n = blockIdx.x * 16 + (t >> 4);
    const int k = t & 15;
    if (n >= NN) return;
    const float* hr = h1 + (size_t)n * 64;
    float acc = 0.f;
    #pragma unroll
    for (int c = 0; c < 64; ++c) acc += hr[c] * sW[c * 16 + k];
    h2b[(size_t)n * 16 + k] = f2bf(acc);
    float vs = acc * a2s[k], vd = acc * a2d[k];
    #pragma unroll
    for (int off = 1; off < 16; off <<= 1) {
        vs += __shfl_xor(vs, off, 64);
        vd += __shfl_xor(vd, off, 64);
    }
    if (k == 0) { al2s[n] = vs; al2d[n] = vd; }
}

// ---------- layer 2 aggregation + log_softmax ----------
__global__ __launch_bounds__(256) void k_agg2(
    const int* __restrict__ row, const int* __restrict__ adj,
    const float* __restrict__ al2s, const float* __restrict__ al2d,
    const unsigned short* __restrict__ h2b, const float* __restrict__ b2,
    float* __restrict__ out)
{
    const int wv = threadIdx.x >> 6, lane = threadIdx.x & 63;
    const int n = blockIdx.x * 4 + wv;
    const float ald = al2d[n];
    const int r0 = row[n], r1 = row[n + 1];

    // --- max pre-pass: 64 edges per iteration ---
    float m = -1e30f;
    for (int i = r0 + lane; i < r1; i += 64)
        m = fmaxf(m, lrelu(al2s[adj[i]] + ald));
    #pragma unroll
    for (int off = 1; off < 64; off <<= 1)
        m = fmaxf(m, __shfl_xor(m, off, 64));

    // --- main: 4 edge-groups x 16 channels ---
    const int k = lane & 15, j = lane >> 4;
    float dsum = 0.f, acc = 0.f;
    for (int i = r0 + j; i < r1; i += 4) {
        int s = adj[i];
        float w = __expf(lrelu(al2s[s] + ald) - m);
        dsum += w;
        acc  += w * bf2f(h2b[(size_t)s * 16 + k]);
    }
    #pragma unroll
    for (int off = 16; off < 64; off <<= 1) {
        dsum += __shfl_xor(dsum, off, 64);
        acc  += __shfl_xor(acc, off, 64);
    }
    float v = acc / dsum + b2[k];
    float mx = v;
    #pragma unroll
    for (int off = 1; off < 16; off <<= 1) mx = fmaxf(mx, __shfl_xor(mx, off, 64));
    float se = __expf(v - mx);
    #pragma unroll
    for (int off = 1; off < 16; off <<= 1) se += __shfl_xor(se, off, 64);
    float ls = mx + __logf(se);
    if (j == 0) out[(size_t)n * 16 + k] = v - ls;
}

extern "C" void kernel_launch(void* const* d_in, const int* in_sizes, int n_in,
                              void* d_out, int out_size, void* d_ws, size_t ws_size,
                              hipStream_t stream)
{
    const float* x    = (const float*)d_in[0];
    const int*   eidx = (const int*)d_in[1];
    const float* W1   = (const float*)d_in[2];
    const float* a1s  = (const float*)d_in[3];
    const float* a1d  = (const float*)d_in[4];
    const float* b1   = (const float*)d_in[5];
    const float* W2   = (const float*)d_in[6];
    const float* a2s  = (const float*)d_in[7];
    const float* a2d  = (const float*)d_in[8];
    const float* b2   = (const float*)d_in[9];
    float* out = (float*)d_out;
    float* ws  = (float*)d_ws;

    const int* esrc = eidx;
    const int* edst = eidx + EE;

    int* deg  = (int*)(ws + OFF_DEG);
    int* cnt  = (int*)(ws + OFF_CNT);
    int* row  = (int*)(ws + OFF_ROW);
    int* tmp  = (int*)(ws + OFF_TMP);
    int* bsum = (int*)(ws + OFF_BSUM);
    int* adj  = (int*)(ws + OFF_ADJ);
    unsigned short* h1b = (unsigned short*)(ws + OFF_H1B);
    float* al1s  = ws + OFF_AL1S;
    float* al1d  = ws + OFF_AL1D;
    float* h1    = ws + OFF_H1;
    unsigned short* h2b = (unsigned short*)(ws + OFF_H2B);
    float* al2s  = ws + OFF_AL2S;
    float* al2d  = ws + OFF_AL2D;

    hipMemsetAsync(ws, 0, (size_t)NZERO_I * sizeof(int), stream);

    const int gE = (NEDGE + 255) / 256;
    k_hist <<<gE,   256, 0, stream>>>(edst, deg);
    k_scan1<<<NBLK, 256, 0, stream>>>(deg, tmp, bsum);
    k_scan2<<<1,    512, 0, stream>>>(bsum);
    k_scan3<<<NBLK, 256, 0, stream>>>(tmp, bsum, row);
    k_fill <<<gE,   256, 0, stream>>>(esrc, edst, row, cnt, adj);

    k_gemm1<<<(NN + 63) / 64, 256, 0, stream>>>(x, W1, a1s, a1d, h1b, al1s, al1d);
    k_agg1 <<<NN / 4, 256, 0, stream>>>(row, adj, al1s, al1d, h1b, b1, h1);
    k_gemm2<<<NN / 16, 256, 0, stream>>>(h1, W2, a2s, a2d, h2b, al2s, al2d);
    k_agg2 <<<NN / 4, 256, 0, stream>>>(row, adj, al2s, al2d, h2b, b2, out);
}